// Round 14
// baseline (261.070 us; speedup 1.0000x reference)
//
#include <hip/hip_runtime.h>

// SVSAlgorithm: per-pixel sequential threshold recurrence over T frames,
// fused with 3x3 constant-kernel "DiffErosion" conv + relu epilogue.
//
// Two-launch design. Closed dead-ends: kernel-role fusion (R5/R8/R10);
// float2/VGPR-deep scan pipelines (R6/R7/R11/R12 -- compiler sinks or
// serializes VGPR prefetch targets); 32x8 aligned-write tiles (R13: write
// amp 1.0 achieved but halo FETCH exploded 120->268MB, net -21us loss).
// Proven: compute<64> 16x16 tile BUF=16 ~87-90us (R11); scalar scan 50us.
//
//  L1 svs_scan_lds<64>: NEW - global_load_lds pipeline. 320 blocks x 64 thr
//     (1 wave), DEPTH=63 frames staged in LDS (16128B). No VGPR dests ->
//     the load-sinking pathology is structurally impossible; depth bounded
//     by vmcnt (63) not registers. 5MB in flight device-wide ~ BW*latency.
//     Consume loop: manual s_waitcnt vmcnt(DEPTH-4) (margin for snapshot
//     stores sharing the counter) + sched_barrier(0), ds_read next frame
//     while current frame's chain update runs, then refill the freed slot.
//     Slot overwrite safe: value is in a register (compiler lgkmcnt wait
//     precedes use) before the refill issues; sched_barrier(0) pins order.
//  L2 svs_compute<64>: R11-proven verbatim (16x16 tile, 14x14 interior,
//     BUF=16, DPP conv, XCD-grouped remap). Sigmoid exp2(fma)+v_rcp;
//     state updates replicate reference f32 op order exactly.
//  ws ladder: SNAP=64 (5.08MB) -> SNAP=128 scalar scan -> single-slice.

#define TILE_W 16
#define TILE_H 16
#define IN_W 14
#define IN_H 14
#define BUF 16       // frames per LDS stage in compute pass
#define PRE 32       // scalar-scan prefetch half-depth (fallback path)
#define DEPTH 63     // scan_lds: frames in flight (vmcnt cap)

constexpr int T_FRAMES = 2048;
constexpr int H_IMG = 128;
constexpr int W_IMG = 160;
constexpr int HW = H_IMG * W_IMG;
constexpr float C1 = 721.3475204444817f;         // 500 * log2(e)

constexpr size_t ws_needed(int snap) {
    return (size_t)(T_FRAMES / snap - 1) * HW * sizeof(float2);
}

__device__ __forceinline__ float dpp_from_left(float v) {   // lane n <- lane n-1 (16-lane rows)
    return __int_as_float(__builtin_amdgcn_update_dpp(0, __float_as_int(v), 0x111, 0xF, 0xF, true));
}
__device__ __forceinline__ float dpp_from_right(float v) {  // lane n <- lane n+1
    return __int_as_float(__builtin_amdgcn_update_dpp(0, __float_as_int(v), 0x101, 0xF, 0xF, true));
}

// gfx9 s_waitcnt imm: vmcnt[3:0]@[3:0], expcnt@[6:4], lgkmcnt@[11:8], vmcnt[5:4]@[15:14]
#define WAITCNT_VM(N) __builtin_amdgcn_s_waitcnt((((N) & 0xF) | (((N) >> 4) << 14) | (0x7 << 4) | (0xF << 8)))
#define SB0() __builtin_amdgcn_sched_barrier(0)

// addrspace casts via integer (LLVM lowers generic->LDS addrspacecast as
// truncation: low 32 bits of a generic LDS address ARE the LDS offset)
typedef const unsigned int __attribute__((address_space(1)))* gas_ptr;
typedef unsigned int __attribute__((address_space(3)))* las_ptr;
#define GLLDS(g, l)                                                          \
    __builtin_amdgcn_global_load_lds(                                        \
        (gas_ptr)(unsigned long long)(g),                                    \
        (las_ptr)(unsigned)(unsigned long long)(l), 4, 0, 0)

// ---------------- L1: scan via global_load_lds pipeline -------------------
template <int SNAP_>
__global__ __launch_bounds__(64, 1)
void svs_scan_lds(const float* __restrict__ x, const float* __restrict__ params,
                  const float* __restrict__ HT0, const float* __restrict__ LT0,
                  float2* __restrict__ snap)
{
    constexpr int TEFF_ = T_FRAMES - SNAP_;      // 1984: tail never consumed
    constexpr int NSNAP_ = T_FRAMES / SNAP_ - 1;
    const int lane = (int)threadIdx.x;
    const int pix  = (int)blockIdx.x * 64 + lane;   // 320 blocks x 64
    const float dC = params[0];
    const float dO = params[1];

    float HT = HT0[pix];
    float LT = LT0[pix];
    const float* xp = x + pix;

    __shared__ float lds[DEPTH * 64];

    // prologue: fill all DEPTH slots (one 256B coalesced request each)
    #pragma unroll 1
    for (int d = 0; d < DEPTH; ++d)
        GLLDS(xp + (size_t)d * HW, &lds[d * 64]);

    WAITCNT_VM(DEPTH - 1);                        // slot 0 landed
    SB0();
    float img_next = lds[lane];                   // frame 0

    int wslot = 0;   // slot of frame f (to refill after consumption)
    int rslot = 1;   // slot of frame f+1 (to read this iteration)

    #pragma unroll 1
    for (int f = 0; f < TEFF_; ++f) {
        const float img = img_next;               // frame f value now in reg
        if (f + 1 < TEFF_) {
            WAITCNT_VM(DEPTH - 4);                // f+1's load done (margin 2
            SB0();                                //  for snapshot stores)
            img_next = lds[rslot * 64 + lane];
        }
        HT = ((img - HT) > 0.0f) ? (HT + dO) : (HT - dC);
        LT = ((LT - img) > 0.0f) ? (LT - dO) : (LT + dC);
        SB0();                                    // keep refill below the read
        if (f + DEPTH < TEFF_)
            GLLDS(xp + (size_t)(f + DEPTH) * HW, &lds[wslot * 64]);
        if ((f & (SNAP_ - 1)) == (SNAP_ - 1)) {
            const int k = f / SNAP_;              // 0..NSNAP_-1
            if (k < NSNAP_)
                snap[(size_t)k * HW + pix] = make_float2(HT, LT);
        }
        if (++wslot == DEPTH) wslot = 0;
        if (++rslot == DEPTH) rslot = 0;
    }
}

// ---------------- L2: per-slice fused compute (R11-proven) ----------------
template <int SNAP_>
__global__ __launch_bounds__(256)
void svs_compute(const float* __restrict__ x, const float* __restrict__ params,
                 const float* __restrict__ HT0, const float* __restrict__ LT0,
                 const float* __restrict__ kern, const float2* __restrict__ snap,
                 float* __restrict__ out)
{
    constexpr int TOTAL_ = 120 * (T_FRAMES / SNAP_);
    // XCD-grouped remap: contiguous chunks of linear block id per XCD so
    // adjacent-bx tiles (sharing output cache lines) land on one XCD L2.
    const int lin = (int)blockIdx.x + 12 * (int)blockIdx.y + 120 * (int)blockIdx.z;
    const int w   = (lin & 7) * (TOTAL_ / 8) + (lin >> 3);   // TOTAL_%8==0 -> bijective
    const int bx  = w % 12;
    const int by  = (w / 12) % 10;
    const int slice = w / 120;

    const int tx = threadIdx.x & 15;
    const int ty = threadIdx.x >> 4;
    const int gx = bx * IN_W + tx - 1;
    const int gy = by * IN_H + ty - 1;
    const int t0 = slice * SNAP_;

    const bool valid = (gx >= 0) & (gx < W_IMG) & (gy >= 0) & (gy < H_IMG);
    const int cx = min(max(gx, 0), W_IMG - 1);
    const int cy = min(max(gy, 0), H_IMG - 1);
    const int pix = cy * W_IMG + cx;

    const float dC   = params[0];
    const float dO   = params[1];
    const float dHot = params[2];
    const float kw   = kern[4];        // all 9 weights equal (2/9)
    const float c0   = dHot * C1;      // exp2 arg = fma(a, -C1, c0)

    float HT, LT;
    if (slice == 0) {
        HT = valid ? HT0[pix] : 0.0f;
        LT = valid ? LT0[pix] : 0.0f;
    } else {
        const float2 s = snap[(size_t)(slice - 1) * HW + pix];
        HT = valid ? s.x : 0.0f;
        LT = valid ? s.y : 0.0f;
    }

    // sm[row][frame][col]: row stride BUF*17=272 floats == 16 mod 32 banks ->
    // wave's 4 row-clusters at bank shifts {0,16,0,16}: 2-way max (free).
    __shared__ float sm[TILE_H][BUF][TILE_W + 1];

    const bool doOut = (tx >= 1) & (tx <= IN_W) & (ty >= 1) & (ty <= IN_H) & valid;
    const int ym = max(ty - 1, 0);
    const int yp = min(ty + 1, TILE_H - 1);
    const float* xp = x + pix;
    float* op = out + pix;

    for (int tb = t0; tb < t0 + SNAP_; tb += BUF) {
        float v[BUF], hot[BUF];
        #pragma unroll
        for (int i = 0; i < BUF; ++i) v[i] = xp[(tb + i) * HW];
        #pragma unroll
        for (int i = 0; i < BUF; ++i) {
            const float img = v[i];
            const float aH = img - HT;
            const float eH = __builtin_amdgcn_exp2f(fmaf(aH, -C1, c0));
            const float hH = __builtin_amdgcn_rcpf(1.0f + eH);
            HT = (aH > 0.0f) ? (HT + dO) : (HT - dC);
            const float aL = LT - img;
            const float eL = __builtin_amdgcn_exp2f(fmaf(aL, -C1, c0));
            const float hL = __builtin_amdgcn_rcpf(1.0f + eL);
            LT = (aL > 0.0f) ? (LT - dO) : (LT + dC);
            hot[i] = valid ? (hH + hL) : 1.0f;
            sm[ty][i][tx] = hot[i];
        }
        __syncthreads();
        #pragma unroll
        for (int i = 0; i < BUF; ++i) {
            const float r0 = sm[ym][i][tx];
            const float r1 = sm[yp][i][tx];
            const float vs = r0 + hot[i] + r1;               // vertical box sum
            const float S  = vs + dpp_from_left(vs) + dpp_from_right(vs);
            float o = fmaf(S, kw, -1.0f);                    // 1 - kw*(9-S) = kw*S - 1
            o = fmaxf(o, 0.0f);
            if (doOut) op[(tb + i) * HW] = o;
        }
        __syncthreads();
    }
}

// ---------------- scalar scan (fallback ladder, R9-proven) ----------------
template <int SNAP_>
__global__ __launch_bounds__(256, 1)
void svs_scan(const float* __restrict__ x, const float* __restrict__ params,
              const float* __restrict__ HT0, const float* __restrict__ LT0,
              float2* __restrict__ snap)
{
    constexpr int TEFF_ = T_FRAMES - SNAP_;
    const int pix = (int)blockIdx.x * 256 + (int)threadIdx.x;
    const float dC = params[0];
    const float dO = params[1];

    float HT = HT0[pix];
    float LT = LT0[pix];
    const float* xp = x + pix;

    float va[PRE], vb[PRE];
    #pragma unroll
    for (int i = 0; i < PRE; ++i) va[i] = xp[i * HW];
    __builtin_amdgcn_sched_barrier(0);

    for (int t = 0; t < TEFF_; t += 2 * PRE) {
        #pragma unroll
        for (int i = 0; i < PRE; ++i) vb[i] = xp[(t + PRE + i) * HW];
        __builtin_amdgcn_sched_barrier(0);
        #pragma unroll
        for (int i = 0; i < PRE; ++i) {
            const float img = va[i];
            HT = ((img - HT) > 0.0f) ? (HT + dO) : (HT - dC);
            LT = ((LT - img) > 0.0f) ? (LT - dO) : (LT + dC);
        }
        if (((t + PRE) % SNAP_) == 0) {
            const int k = (t + PRE) / SNAP_ - 1;
            if (k >= 0 && k < T_FRAMES / SNAP_ - 1)
                snap[(size_t)k * HW + pix] = make_float2(HT, LT);
        }
        if (t + 2 * PRE < TEFF_) {
            #pragma unroll
            for (int i = 0; i < PRE; ++i) va[i] = xp[(t + 2 * PRE + i) * HW];
        }
        __builtin_amdgcn_sched_barrier(0);
        #pragma unroll
        for (int i = 0; i < PRE; ++i) {
            const float img = vb[i];
            HT = ((img - HT) > 0.0f) ? (HT + dO) : (HT - dC);
            LT = ((LT - img) > 0.0f) ? (LT - dO) : (LT + dC);
        }
        if (((t + 2 * PRE) % SNAP_) == 0) {
            const int k = (t + 2 * PRE) / SNAP_ - 1;
            if (k < T_FRAMES / SNAP_ - 1)
                snap[(size_t)k * HW + pix] = make_float2(HT, LT);
        }
    }
}

extern "C" void kernel_launch(void* const* d_in, const int* in_sizes, int n_in,
                              void* d_out, int out_size, void* d_ws, size_t ws_size,
                              hipStream_t stream) {
    const float* x      = (const float*)d_in[0];
    const float* params = (const float*)d_in[1];
    const float* HT0p   = (const float*)d_in[2];
    const float* LT0p   = (const float*)d_in[3];
    const float* kern   = (const float*)d_in[4];
    float* out = (float*)d_out;

    if (ws_size >= ws_needed(64)) {
        float2* snap = (float2*)d_ws;
        svs_scan_lds<64><<<dim3(HW / 64), dim3(64), 0, stream>>>(
            x, params, HT0p, LT0p, snap);
        svs_compute<64><<<dim3(12, 10, T_FRAMES / 64), dim3(256), 0, stream>>>(
            x, params, HT0p, LT0p, kern, snap, out);
    } else if (ws_size >= ws_needed(128)) {
        float2* snap = (float2*)d_ws;
        svs_scan<128><<<dim3(HW / 256), dim3(256), 0, stream>>>(x, params, HT0p, LT0p, snap);
        svs_compute<128><<<dim3(12, 10, T_FRAMES / 128), dim3(256), 0, stream>>>(
            x, params, HT0p, LT0p, kern, snap, out);
    } else {
        svs_compute<2048><<<dim3(12, 10, 1), dim3(256), 0, stream>>>(
            x, params, HT0p, LT0p, kern, (const float2*)d_ws, out);
    }
}

// Round 15
// 153.695 us; speedup vs baseline: 1.6986x; 1.6986x over previous
//
#include <hip/hip_runtime.h>

// SVSAlgorithm: per-pixel sequential threshold recurrence over T frames,
// fused with 3x3 constant-kernel "DiffErosion" conv + relu epilogue.
//
// Two-launch design: assembly of the two PROVEN-best parts (never benched
// together before -- R12 added a regressing prefetch split on top).
// Closed dead-ends (do NOT revisit): kernel-role fusion (R5/R8/R10: shared
// regalloc collapses scan pipeline); float2 scan (R7/R11); VGPR cross-stage
// prefetch in compute (R12); 32x8 aligned-write tiles (R13: write amp 1.0
// but halo FETCH +148MB); global_load_lds per-frame scan (R14: per-frame
// waitcnt/ds_read serialization, 174us).
//
//  L1 svs_scan<64> (R9, ~50us): 80 blocks x 256 thr, 1 chain/thread, 2x32
//     double-buffered prefetch, each issue block pinned with
//     sched_barrier(0) (stops compiler load-sinking), launch_bounds(256,1).
//     Skips frames >= 1984 (never consumed). Snapshots every 64 frames.
//  L2 svs_compute<64> (R11, ~88us): 16x16 tile, 14x14 interior + halo
//     recompute, BUF=16 stages (8 barrier pairs/slice), plain staging.
//     Sigmoid exp2(fma)+v_rcp; conv == box-sum (all 9 weights equal):
//     vertical = 2 LDS reads + own reg, horizontal via DPP row_shr/shl;
//     LDS sm[row][frame][col] (row stride 272 == 16 mod 32 banks -> 2-way
//     max, free). XCD-grouped remap for output-line L2 merging.
//     State updates replicate reference f32 op order exactly.
//  ws ladder: SNAP=64 (5.08MB) -> SNAP=128 (2.4MB) -> single-slice.

#define TILE_W 16
#define TILE_H 16
#define IN_W 14
#define IN_H 14
#define BUF 16       // frames per LDS stage in compute pass
#define PRE 32       // scan prefetch half-depth (double buffer)

constexpr int T_FRAMES = 2048;
constexpr int H_IMG = 128;
constexpr int W_IMG = 160;
constexpr int HW = H_IMG * W_IMG;
constexpr float C1 = 721.3475204444817f;         // 500 * log2(e)

constexpr size_t ws_needed(int snap) {
    return (size_t)(T_FRAMES / snap - 1) * HW * sizeof(float2);
}

__device__ __forceinline__ float dpp_from_left(float v) {   // lane n <- lane n-1 (16-lane rows)
    return __int_as_float(__builtin_amdgcn_update_dpp(0, __float_as_int(v), 0x111, 0xF, 0xF, true));
}
__device__ __forceinline__ float dpp_from_right(float v) {  // lane n <- lane n+1
    return __int_as_float(__builtin_amdgcn_update_dpp(0, __float_as_int(v), 0x101, 0xF, 0xF, true));
}

// ---------------- L1: state-only scan (R9-proven, scalar, pinned) ---------
template <int SNAP_>
__global__ __launch_bounds__(256, 1)
void svs_scan(const float* __restrict__ x, const float* __restrict__ params,
              const float* __restrict__ HT0, const float* __restrict__ LT0,
              float2* __restrict__ snap)
{
    constexpr int TEFF_ = T_FRAMES - SNAP_;      // tail frames never consumed
    const int pix = (int)blockIdx.x * 256 + (int)threadIdx.x;  // 80 blocks
    const float dC = params[0];
    const float dO = params[1];

    float HT = HT0[pix];
    float LT = LT0[pix];
    const float* xp = x + pix;

    float va[PRE], vb[PRE];
    #pragma unroll
    for (int i = 0; i < PRE; ++i) va[i] = xp[i * HW];
    __builtin_amdgcn_sched_barrier(0);

    for (int t = 0; t < TEFF_; t += 2 * PRE) {
        #pragma unroll
        for (int i = 0; i < PRE; ++i) vb[i] = xp[(t + PRE + i) * HW];
        __builtin_amdgcn_sched_barrier(0);
        #pragma unroll
        for (int i = 0; i < PRE; ++i) {
            const float img = va[i];
            HT = ((img - HT) > 0.0f) ? (HT + dO) : (HT - dC);
            LT = ((LT - img) > 0.0f) ? (LT - dO) : (LT + dC);
        }
        if (((t + PRE) % SNAP_) == 0) {
            const int k = (t + PRE) / SNAP_ - 1;
            if (k >= 0 && k < T_FRAMES / SNAP_ - 1)
                snap[(size_t)k * HW + pix] = make_float2(HT, LT);
        }
        if (t + 2 * PRE < TEFF_) {
            #pragma unroll
            for (int i = 0; i < PRE; ++i) va[i] = xp[(t + 2 * PRE + i) * HW];
        }
        __builtin_amdgcn_sched_barrier(0);
        #pragma unroll
        for (int i = 0; i < PRE; ++i) {
            const float img = vb[i];
            HT = ((img - HT) > 0.0f) ? (HT + dO) : (HT - dC);
            LT = ((LT - img) > 0.0f) ? (LT - dO) : (LT + dC);
        }
        if (((t + 2 * PRE) % SNAP_) == 0) {
            const int k = (t + 2 * PRE) / SNAP_ - 1;
            if (k < T_FRAMES / SNAP_ - 1)
                snap[(size_t)k * HW + pix] = make_float2(HT, LT);
        }
    }
}

// ---------------- L2: per-slice fused compute (R11-proven) ----------------
template <int SNAP_>
__global__ __launch_bounds__(256)
void svs_compute(const float* __restrict__ x, const float* __restrict__ params,
                 const float* __restrict__ HT0, const float* __restrict__ LT0,
                 const float* __restrict__ kern, const float2* __restrict__ snap,
                 float* __restrict__ out)
{
    constexpr int TOTAL_ = 120 * (T_FRAMES / SNAP_);
    // XCD-grouped remap: contiguous chunks of linear block id per XCD so
    // adjacent-bx tiles (sharing output cache lines) land on one XCD L2.
    const int lin = (int)blockIdx.x + 12 * (int)blockIdx.y + 120 * (int)blockIdx.z;
    const int w   = (lin & 7) * (TOTAL_ / 8) + (lin >> 3);   // TOTAL_%8==0 -> bijective
    const int bx  = w % 12;
    const int by  = (w / 12) % 10;
    const int slice = w / 120;

    const int tx = threadIdx.x & 15;
    const int ty = threadIdx.x >> 4;
    const int gx = bx * IN_W + tx - 1;
    const int gy = by * IN_H + ty - 1;
    const int t0 = slice * SNAP_;

    const bool valid = (gx >= 0) & (gx < W_IMG) & (gy >= 0) & (gy < H_IMG);
    const int cx = min(max(gx, 0), W_IMG - 1);
    const int cy = min(max(gy, 0), H_IMG - 1);
    const int pix = cy * W_IMG + cx;

    const float dC   = params[0];
    const float dO   = params[1];
    const float dHot = params[2];
    const float kw   = kern[4];        // all 9 weights equal (2/9)
    const float c0   = dHot * C1;      // exp2 arg = fma(a, -C1, c0)

    float HT, LT;
    if (slice == 0) {
        HT = valid ? HT0[pix] : 0.0f;
        LT = valid ? LT0[pix] : 0.0f;
    } else {
        const float2 s = snap[(size_t)(slice - 1) * HW + pix];
        HT = valid ? s.x : 0.0f;
        LT = valid ? s.y : 0.0f;
    }

    // sm[row][frame][col]: row stride BUF*17=272 floats == 16 mod 32 banks ->
    // wave's 4 row-clusters at bank shifts {0,16,0,16}: 2-way max (free).
    __shared__ float sm[TILE_H][BUF][TILE_W + 1];

    const bool doOut = (tx >= 1) & (tx <= IN_W) & (ty >= 1) & (ty <= IN_H) & valid;
    const int ym = max(ty - 1, 0);
    const int yp = min(ty + 1, TILE_H - 1);
    const float* xp = x + pix;
    float* op = out + pix;

    for (int tb = t0; tb < t0 + SNAP_; tb += BUF) {
        float v[BUF], hot[BUF];
        #pragma unroll
        for (int i = 0; i < BUF; ++i) v[i] = xp[(tb + i) * HW];
        #pragma unroll
        for (int i = 0; i < BUF; ++i) {
            const float img = v[i];
            const float aH = img - HT;
            const float eH = __builtin_amdgcn_exp2f(fmaf(aH, -C1, c0));
            const float hH = __builtin_amdgcn_rcpf(1.0f + eH);
            HT = (aH > 0.0f) ? (HT + dO) : (HT - dC);
            const float aL = LT - img;
            const float eL = __builtin_amdgcn_exp2f(fmaf(aL, -C1, c0));
            const float hL = __builtin_amdgcn_rcpf(1.0f + eL);
            LT = (aL > 0.0f) ? (LT - dO) : (LT + dC);
            hot[i] = valid ? (hH + hL) : 1.0f;
            sm[ty][i][tx] = hot[i];
        }
        __syncthreads();
        #pragma unroll
        for (int i = 0; i < BUF; ++i) {
            const float r0 = sm[ym][i][tx];
            const float r1 = sm[yp][i][tx];
            const float vs = r0 + hot[i] + r1;               // vertical box sum
            const float S  = vs + dpp_from_left(vs) + dpp_from_right(vs);
            float o = fmaf(S, kw, -1.0f);                    // 1 - kw*(9-S) = kw*S - 1
            o = fmaxf(o, 0.0f);
            if (doOut) op[(tb + i) * HW] = o;
        }
        __syncthreads();
    }
}

extern "C" void kernel_launch(void* const* d_in, const int* in_sizes, int n_in,
                              void* d_out, int out_size, void* d_ws, size_t ws_size,
                              hipStream_t stream) {
    const float* x      = (const float*)d_in[0];
    const float* params = (const float*)d_in[1];
    const float* HT0p   = (const float*)d_in[2];
    const float* LT0p   = (const float*)d_in[3];
    const float* kern   = (const float*)d_in[4];
    float* out = (float*)d_out;

    if (ws_size >= ws_needed(64)) {
        float2* snap = (float2*)d_ws;
        svs_scan<64><<<dim3(HW / 256), dim3(256), 0, stream>>>(x, params, HT0p, LT0p, snap);
        svs_compute<64><<<dim3(12, 10, T_FRAMES / 64), dim3(256), 0, stream>>>(
            x, params, HT0p, LT0p, kern, snap, out);
    } else if (ws_size >= ws_needed(128)) {
        float2* snap = (float2*)d_ws;
        svs_scan<128><<<dim3(HW / 256), dim3(256), 0, stream>>>(x, params, HT0p, LT0p, snap);
        svs_compute<128><<<dim3(12, 10, T_FRAMES / 128), dim3(256), 0, stream>>>(
            x, params, HT0p, LT0p, kern, snap, out);
    } else {
        svs_compute<2048><<<dim3(12, 10, 1), dim3(256), 0, stream>>>(
            x, params, HT0p, LT0p, kern, (const float2*)d_ws, out);
    }
}

// Round 16
// 144.011 us; speedup vs baseline: 1.8128x; 1.0672x over previous
//
#include <hip/hip_runtime.h>

// SVSAlgorithm: per-pixel sequential threshold recurrence over T frames,
// fused with 3x3 constant-kernel "DiffErosion" conv + relu epilogue.
//
// FINAL ASSEMBLY = the Round-9 configuration (best measured: 145.9us),
// reinstated verbatim. Ledger of closed dead-ends (do NOT revisit):
//  - kernel-role fusion (R5/R8/R10): shared regalloc collapses the scan
//    pipeline to VGPR~60 regardless of launch_bounds; 6-9x regression.
//  - float2 scan (R7/R11): compiler won't keep 2 float2 buffers live;
//    halves wave count; ~2x scan regression.
//  - VGPR cross-stage prefetch in compute (R12): VGPR=32 collapse, +28us.
//  - 32x8 aligned-write tiles (R13): write amp 1.0 achieved (-46MB) but
//    halo read locality broke (FETCH +148MB), net +21us.
//  - global_load_lds per-frame scan (R14): per-frame waitcnt/ds_read
//    serialization, 174us.
//  - BUF=16 compute (R11/R15): neutral-to-slightly-worse vs BUF=8.
//
//  L1 svs_scan<64> (~50us): 80 blocks x 256 thr, 1 chain/thread, TRIPLE-
//     buffered PRE=32 prefetch (va/vb/vc; ~63 outstanding loads/wave ~
//     5MB in flight device-wide), every issue block pinned with
//     sched_barrier(0) (stops compiler load-sinking -- the R5-R8 collapse
//     mechanism), __launch_bounds__(256,1). Skips frames >= 1984 (never
//     consumed). Snapshots (HT,LT) every 64 frames -> d_ws.
//  L2 svs_compute<64> (~94us): 16x16 tile, 14x14 interior + halo recompute,
//     BUF=8 stages. Sigmoid via exp2(fma)+v_rcp; conv == box-sum (all 9
//     weights equal): vertical = 2 LDS reads + own reg, horizontal via DPP
//     row_shr/row_shl; LDS sm[row][frame][col] (row stride 136 == 8 mod 32
//     banks -> <=2-way, free). XCD-grouped remap for output-line L2
//     merging. State updates replicate reference f32 op order exactly.
//  ws ladder: SNAP=64 (5.08MB) -> SNAP=128 (2.4MB) -> single-slice.

#define TILE_W 16
#define TILE_H 16
#define IN_W 14
#define IN_H 14
#define BUF 8        // frames per LDS stage in compute pass
#define PRE 32       // scan batch size (3 buffers)

constexpr int T_FRAMES = 2048;
constexpr int H_IMG = 128;
constexpr int W_IMG = 160;
constexpr int HW = H_IMG * W_IMG;
constexpr float C1 = 721.3475204444817f;         // 500 * log2(e)

constexpr size_t ws_needed(int snap) {
    return (size_t)(T_FRAMES / snap - 1) * HW * sizeof(float2);
}

__device__ __forceinline__ float dpp_from_left(float v) {   // lane n <- lane n-1 (16-lane rows)
    return __int_as_float(__builtin_amdgcn_update_dpp(0, __float_as_int(v), 0x111, 0xF, 0xF, true));
}
__device__ __forceinline__ float dpp_from_right(float v) {  // lane n <- lane n+1
    return __int_as_float(__builtin_amdgcn_update_dpp(0, __float_as_int(v), 0x101, 0xF, 0xF, true));
}

// ---------------- L1: state-only scan, triple-buffered pinned prefetch ----
#define S_ISSUE(V, F)                              \
    _Pragma("unroll")                              \
    for (int i = 0; i < PRE; ++i) V[i] = xp[((F) + i) * HW];

#define S_COMP(V)                                  \
    _Pragma("unroll")                              \
    for (int i = 0; i < PRE; ++i) {                \
        const float img = V[i];                    \
        HT = ((img - HT) > 0.0f) ? (HT + dO) : (HT - dC); \
        LT = ((LT - img) > 0.0f) ? (LT - dO) : (LT + dC); \
    }

template <int SNAP_>
__global__ __launch_bounds__(256, 1)
void svs_scan(const float* __restrict__ x, const float* __restrict__ params,
              const float* __restrict__ HT0, const float* __restrict__ LT0,
              float2* __restrict__ snap)
{
    // frames >= TEFF are never consumed (last snapshot = state after TEFF-1)
    constexpr int TEFF = T_FRAMES - SNAP_;
    const int pix = (int)blockIdx.x * 256 + (int)threadIdx.x;  // 80 blocks
    const float dC = params[0];
    const float dO = params[1];

    float HT = HT0[pix];
    float LT = LT0[pix];
    const float* xp = x + pix;

    auto maybe_snap = [&](int endf) {
        if ((endf % SNAP_) == 0) {
            const int k = endf / SNAP_ - 1;
            if (k < T_FRAMES / SNAP_ - 1)
                snap[(size_t)k * HW + pix] = make_float2(HT, LT);
        }
    };

    float va[PRE], vb[PRE], vc[PRE];
    S_ISSUE(va, 0)
    S_ISSUE(vb, PRE)
    __builtin_amdgcn_sched_barrier(0);

    for (int t = 0; t < TEFF; t += 3 * PRE) {
        if (t + 2 * PRE < TEFF) { S_ISSUE(vc, t + 2 * PRE) }
        __builtin_amdgcn_sched_barrier(0);
        S_COMP(va)
        maybe_snap(t + PRE);
        if (t + 3 * PRE < TEFF) { S_ISSUE(va, t + 3 * PRE) }
        __builtin_amdgcn_sched_barrier(0);
        if (t + PRE < TEFF) {
            S_COMP(vb)
            maybe_snap(t + 2 * PRE);
        }
        if (t + 4 * PRE < TEFF) { S_ISSUE(vb, t + 4 * PRE) }
        __builtin_amdgcn_sched_barrier(0);
        if (t + 2 * PRE < TEFF) {
            S_COMP(vc)
            maybe_snap(t + 3 * PRE);
        }
    }
}

// ---------------- L2: per-slice fused compute (R9-proven) -----------------
template <int SNAP_>
__global__ __launch_bounds__(256)
void svs_compute(const float* __restrict__ x, const float* __restrict__ params,
                 const float* __restrict__ HT0, const float* __restrict__ LT0,
                 const float* __restrict__ kern, const float2* __restrict__ snap,
                 float* __restrict__ out)
{
    constexpr int NSLICE_ = T_FRAMES / SNAP_;
    constexpr int TOTAL_ = 120 * NSLICE_;
    // XCD-grouped remap: contiguous chunks of linear block id per XCD so
    // adjacent-bx tiles (sharing output cache lines) land on one XCD L2.
    const int lin = (int)blockIdx.x + 12 * (int)blockIdx.y + 120 * (int)blockIdx.z;
    const int w   = (lin & 7) * (TOTAL_ / 8) + (lin >> 3);   // TOTAL_%8==0 -> bijective
    const int bx  = w % 12;
    const int by  = (w / 12) % 10;
    const int slice = w / 120;

    const int tx = threadIdx.x & 15;
    const int ty = threadIdx.x >> 4;
    const int gx = bx * IN_W + tx - 1;
    const int gy = by * IN_H + ty - 1;
    const int t0 = slice * SNAP_;

    const bool valid = (gx >= 0) & (gx < W_IMG) & (gy >= 0) & (gy < H_IMG);
    const int cx = min(max(gx, 0), W_IMG - 1);
    const int cy = min(max(gy, 0), H_IMG - 1);
    const int pix = cy * W_IMG + cx;

    const float dC   = params[0];
    const float dO   = params[1];
    const float dHot = params[2];
    const float kw   = kern[4];        // all 9 weights equal (2/9)
    const float c0   = dHot * C1;      // exp2 arg = fma(a, -C1, c0)

    float HT, LT;
    if (slice == 0) {
        HT = valid ? HT0[pix] : 0.0f;
        LT = valid ? LT0[pix] : 0.0f;
    } else {
        const float2 s = snap[(size_t)(slice - 1) * HW + pix];
        HT = valid ? s.x : 0.0f;
        LT = valid ? s.y : 0.0f;
    }

    // sm[row][frame][col]: row stride 136 floats == 8 mod 32 banks ->
    // wave's 4 row-clusters at bank shifts {0,8,16,24}: <=2-way (free).
    __shared__ float sm[TILE_H][BUF][TILE_W + 1];

    const bool doOut = (tx >= 1) & (tx <= IN_W) & (ty >= 1) & (ty <= IN_H) & valid;
    const int ym = max(ty - 1, 0);
    const int yp = min(ty + 1, TILE_H - 1);
    const float* xp = x + pix;
    float* op = out + pix;

    for (int tb = t0; tb < t0 + SNAP_; tb += BUF) {
        float v[BUF], hot[BUF];
        #pragma unroll
        for (int i = 0; i < BUF; ++i) v[i] = xp[(tb + i) * HW];
        #pragma unroll
        for (int i = 0; i < BUF; ++i) {
            const float img = v[i];
            const float aH = img - HT;
            const float eH = __builtin_amdgcn_exp2f(fmaf(aH, -C1, c0));
            const float hH = __builtin_amdgcn_rcpf(1.0f + eH);
            HT = (aH > 0.0f) ? (HT + dO) : (HT - dC);
            const float aL = LT - img;
            const float eL = __builtin_amdgcn_exp2f(fmaf(aL, -C1, c0));
            const float hL = __builtin_amdgcn_rcpf(1.0f + eL);
            LT = (aL > 0.0f) ? (LT - dO) : (LT + dC);
            hot[i] = valid ? (hH + hL) : 1.0f;
            sm[ty][i][tx] = hot[i];
        }
        __syncthreads();
        #pragma unroll
        for (int i = 0; i < BUF; ++i) {
            const float r0 = sm[ym][i][tx];
            const float r1 = sm[yp][i][tx];
            const float vs = r0 + hot[i] + r1;               // vertical box sum
            const float S  = vs + dpp_from_left(vs) + dpp_from_right(vs);
            float o = fmaf(S, kw, -1.0f);                    // 1 - kw*(9-S) = kw*S - 1
            o = fmaxf(o, 0.0f);
            if (doOut) op[(tb + i) * HW] = o;
        }
        __syncthreads();
    }
}

extern "C" void kernel_launch(void* const* d_in, const int* in_sizes, int n_in,
                              void* d_out, int out_size, void* d_ws, size_t ws_size,
                              hipStream_t stream) {
    const float* x      = (const float*)d_in[0];
    const float* params = (const float*)d_in[1];
    const float* HT0p   = (const float*)d_in[2];
    const float* LT0p   = (const float*)d_in[3];
    const float* kern   = (const float*)d_in[4];
    float* out = (float*)d_out;

    if (ws_size >= ws_needed(64)) {
        float2* snap = (float2*)d_ws;
        svs_scan<64><<<dim3(HW / 256), dim3(256), 0, stream>>>(x, params, HT0p, LT0p, snap);
        svs_compute<64><<<dim3(12, 10, T_FRAMES / 64), dim3(256), 0, stream>>>(
            x, params, HT0p, LT0p, kern, snap, out);
    } else if (ws_size >= ws_needed(128)) {
        float2* snap = (float2*)d_ws;
        svs_scan<128><<<dim3(HW / 256), dim3(256), 0, stream>>>(x, params, HT0p, LT0p, snap);
        svs_compute<128><<<dim3(12, 10, T_FRAMES / 128), dim3(256), 0, stream>>>(
            x, params, HT0p, LT0p, kern, snap, out);
    } else {
        svs_compute<2048><<<dim3(12, 10, 1), dim3(256), 0, stream>>>(
            x, params, HT0p, LT0p, kern, (const float2*)d_ws, out);
    }
}